// Round 3
// baseline (531.226 us; speedup 1.0000x reference)
//
#include <hip/hip_runtime.h>
#include <hip/hip_bf16.h>
#include <stdint.h>

typedef __attribute__((ext_vector_type(8))) short bf16x8;
typedef __attribute__((ext_vector_type(4))) float f32x4;
typedef __attribute__((ext_vector_type(4))) unsigned short u16x4;

#define B_  4
#define T_  2048
#define D_  1024
#define BM  128
#define BN  128
#define BK  32
#define LDT 40   // padded row length (elements) for TN LDS tiles; 80B rows, 16B-aligned

__device__ __forceinline__ float bf2f(ushort u) {
  union { unsigned int i; float f; } v; v.i = ((unsigned int)u) << 16; return v.f;
}
__device__ __forceinline__ ushort f2bf(float f) {
  return (ushort)(__bfloat16_as_ushort(__float2bfloat16(f)));
}

__device__ __forceinline__ void async16(const void* g, void* l) {
  __builtin_amdgcn_global_load_lds(
      (const __attribute__((address_space(1))) void*)g,
      (__attribute__((address_space(3))) void*)l, 16, 0, 0);
}

// chunk swizzle: spreads the 4 16B chunks of a 64B k-row across banks by row
__device__ __forceinline__ int swz4(int r) { return (r ^ (r >> 2)) & 3; }

// fp32 -> bf16 convert, 4 elems/thread, exact-sized grid (n % 1024 == 0).
__global__ __launch_bounds__(256)
void cvt_f32_bf16(const float* __restrict__ in, ushort* __restrict__ out, long n4)
{
  const long i = (long)blockIdx.x * 256 + threadIdx.x;
  if (i >= n4) return;
  const float4 v = *(const float4*)(in + i * 4);
  u16x4 o;
  o[0] = f2bf(v.x); o[1] = f2bf(v.y); o[2] = f2bf(v.z); o[3] = f2bf(v.w);
  *(u16x4*)(out + i * 4) = o;
}

// C[m,n] = sum_k A[m,k] * B[n,k] (+ bias[n]); A:[M,K] k-contig, B:[N,K] k-contig.
// ldc == N. Batched via blockIdx.z with element strides sA/sB/sC.
template<bool OUT_F32, bool HAS_BIAS>
__global__ __launch_bounds__(256, 2)
void gemm_nt(const ushort* __restrict__ A, const ushort* __restrict__ B,
             const float* __restrict__ bias, void* __restrict__ C,
             int N, int K, long sA, long sB, long sC)
{
  __shared__ alignas(16) ushort As[BM * BK];
  __shared__ alignas(16) ushort Bs[BN * BK];
  const int tid  = threadIdx.x;
  const int wave = tid >> 6;
  const int lane = tid & 63;
  const int wm   = wave >> 1;
  const int wn   = wave & 1;
  const int bz   = blockIdx.z;
  const int tileN = blockIdx.x * BN;
  const int tileM = blockIdx.y * BM;
  A += (long)bz * sA;
  B += (long)bz * sB;

  const int lrow   = lane >> 2;                    // 0..15 row within 16-row group
  const int lchunk = (lane & 3) ^ swz4(lrow);      // global k-chunk this lds slot receives

  f32x4 acc[4][4];
#pragma unroll
  for (int i = 0; i < 4; ++i)
#pragma unroll
    for (int j = 0; j < 4; ++j) acc[i][j] = (f32x4){0.f, 0.f, 0.f, 0.f};

  const int frow = lane & 15;
  const int kg   = lane >> 4;
  const int coff = ((kg ^ swz4(frow)) << 3);       // element offset of the 16B chunk

  for (int kt = 0; kt < K; kt += BK) {
    __syncthreads();
#pragma unroll
    for (int i = 0; i < 2; ++i) {
      const int rg  = wave * 2 + i;                // 0..7 (16-row group)
      const int row = rg * 16 + lrow;
      async16(A + (long)(tileM + row) * K + kt + lchunk * 8, (void*)(As + rg * 16 * BK));
      async16(B + (long)(tileN + row) * K + kt + lchunk * 8, (void*)(Bs + rg * 16 * BK));
    }
    __syncthreads();
    bf16x8 af[4], bfr[4];
#pragma unroll
    for (int mi = 0; mi < 4; ++mi)
      af[mi] = *(const bf16x8*)(As + (wm * 64 + mi * 16 + frow) * BK + coff);
#pragma unroll
    for (int ni = 0; ni < 4; ++ni)
      bfr[ni] = *(const bf16x8*)(Bs + (wn * 64 + ni * 16 + frow) * BK + coff);
#pragma unroll
    for (int mi = 0; mi < 4; ++mi)
#pragma unroll
      for (int ni = 0; ni < 4; ++ni)
        acc[mi][ni] = __builtin_amdgcn_mfma_f32_16x16x32_bf16(af[mi], bfr[ni], acc[mi][ni], 0, 0, 0);
  }

  // epilogue: C/D layout col = lane&15, row = (lane>>4)*4 + reg  [m89-verified]
  const int rowbase = tileM + wm * 64 + ((lane >> 4) << 2);
  const int colbase = tileN + wn * 64 + (lane & 15);
#pragma unroll
  for (int ni = 0; ni < 4; ++ni) {
    const int col = colbase + ni * 16;
    float bv = 0.f;
    if constexpr (HAS_BIAS) bv = bias[col];
#pragma unroll
    for (int mi = 0; mi < 4; ++mi) {
#pragma unroll
      for (int r = 0; r < 4; ++r) {
        const int row = rowbase + mi * 16 + r;
        const float v = acc[mi][ni][r] + bv;
        const long idx = (long)bz * sC + (long)row * N + col;
        if constexpr (OUT_F32) ((float*)C)[idx] = v;
        else ((ushort*)C)[idx] = f2bf(v);
      }
    }
  }
}

// C[m,n] = sum_k A[k,m] * B[k,n]; both operands k-major rows.
// MT[d,e] = sum_q ov[q,d] * l[q,e]. Batched via blockIdx.z. bf16 out.
__global__ __launch_bounds__(256, 2)
void gemm_tn(const ushort* __restrict__ A, const ushort* __restrict__ B,
             ushort* __restrict__ C,
             int N, int K, int lda, int ldb, long sA, long sB, long sC)
{
  __shared__ alignas(16) ushort AsT[BM * LDT];
  __shared__ alignas(16) ushort BsT[BN * LDT];
  const int tid  = threadIdx.x;
  const int wave = tid >> 6;
  const int lane = tid & 63;
  const int wm   = wave >> 1;
  const int wn   = wave & 1;
  const int bz   = blockIdx.z;
  const int tileN = blockIdx.x * BN;
  const int tileM = blockIdx.y * BM;
  A += (long)bz * sA;
  B += (long)bz * sB;

  f32x4 acc[4][4];
#pragma unroll
  for (int i = 0; i < 4; ++i)
#pragma unroll
    for (int j = 0; j < 4; ++j) acc[i][j] = (f32x4){0.f, 0.f, 0.f, 0.f};

  const int tk = tid >> 4;          // 0..15 k-row within half
  const int tm = (tid & 15) << 3;   // 8-element column start
  const int frow = lane & 15;
  const int kg   = lane >> 4;

  for (int kt = 0; kt < K; kt += BK) {
    __syncthreads();
#pragma unroll
    for (int h = 0; h < 2; ++h) {
      const int krow = h * 16 + tk;
      bf16x8 va = *(const bf16x8*)(A + (long)(kt + krow) * lda + tileM + tm);
      bf16x8 vb = *(const bf16x8*)(B + (long)(kt + krow) * ldb + tileN + tm);
#pragma unroll
      for (int j = 0; j < 8; ++j) {
        AsT[(tm + j) * LDT + krow] = (ushort)va[j];
        BsT[(tm + j) * LDT + krow] = (ushort)vb[j];
      }
    }
    __syncthreads();
    bf16x8 af[4], bfr[4];
#pragma unroll
    for (int mi = 0; mi < 4; ++mi)
      af[mi] = *(const bf16x8*)(AsT + (wm * 64 + mi * 16 + frow) * LDT + (kg << 3));
#pragma unroll
    for (int ni = 0; ni < 4; ++ni)
      bfr[ni] = *(const bf16x8*)(BsT + (wn * 64 + ni * 16 + frow) * LDT + (kg << 3));
#pragma unroll
    for (int mi = 0; mi < 4; ++mi)
#pragma unroll
      for (int ni = 0; ni < 4; ++ni)
        acc[mi][ni] = __builtin_amdgcn_mfma_f32_16x16x32_bf16(af[mi], bfr[ni], acc[mi][ni], 0, 0, 0);
  }

  const int rowbase = tileM + wm * 64 + ((lane >> 4) << 2);
  const int colbase = tileN + wn * 64 + (lane & 15);
#pragma unroll
  for (int ni = 0; ni < 4; ++ni) {
    const int col = colbase + ni * 16;
#pragma unroll
    for (int mi = 0; mi < 4; ++mi) {
#pragma unroll
      for (int r = 0; r < 4; ++r) {
        const int row = rowbase + mi * 16 + r;
        C[(long)bz * sC + (long)row * N + col] = f2bf(acc[mi][ni][r]);
      }
    }
  }
}

// row softmax over last dim (D_=1024), bf16 in/out, in-place safe.
__global__ __launch_bounds__(256)
void softmax_row(const ushort* __restrict__ S, ushort* __restrict__ O)
{
  const long base = (long)blockIdx.x * D_;
  const int tid = threadIdx.x;
  float v[4];
#pragma unroll
  for (int i = 0; i < 4; ++i) v[i] = bf2f(S[base + i * 256 + tid]);
  float m = fmaxf(fmaxf(v[0], v[1]), fmaxf(v[2], v[3]));
#pragma unroll
  for (int off = 32; off; off >>= 1) m = fmaxf(m, __shfl_xor(m, off));
  __shared__ float redm[4], reds[4];
  const int wv = tid >> 6;
  if ((tid & 63) == 0) redm[wv] = m;
  __syncthreads();
  m = fmaxf(fmaxf(redm[0], redm[1]), fmaxf(redm[2], redm[3]));
  float e[4], s = 0.f;
#pragma unroll
  for (int i = 0; i < 4; ++i) { e[i] = __expf(v[i] - m); s += e[i]; }
#pragma unroll
  for (int off = 32; off; off >>= 1) s += __shfl_xor(s, off);
  if ((tid & 63) == 0) reds[wv] = s;
  __syncthreads();
  s = reds[0] + reds[1] + reds[2] + reds[3];
  const float inv = 1.f / s;
#pragma unroll
  for (int i = 0; i < 4; ++i)
    O[base + i * 256 + tid] = f2bf(e[i] * inv);
}

// column softmax (over T_ rows) pass 1: per-chunk online max/sum.
// grid: (D_/256, 16, B_); chunk = 128 rows. bf16 logits in.
__global__ __launch_bounds__(256)
void colsoft_part(const ushort* __restrict__ S, float* __restrict__ pmax, float* __restrict__ psum)
{
  const int d = blockIdx.x * 256 + threadIdx.x;
  const int c = blockIdx.y;
  const int b = blockIdx.z;
  const ushort* p = S + ((long)b * T_ + (long)c * 128) * D_ + d;
  float m = -3.0e38f, s = 0.f;
#pragma unroll 4
  for (int r = 0; r < 128; ++r) {
    const float x = bf2f(p[(long)r * D_]);
    if (x > m) { s = s * __expf(m - x) + 1.f; m = x; }
    else       { s += __expf(x - m); }
  }
  const long o = ((long)b * 16 + c) * D_ + d;
  pmax[o] = m;
  psum[o] = s;
}

// pass 2: combine 16 chunk partials -> colmax, 1/colsum. grid: (D_/256, B_)
__global__ __launch_bounds__(256)
void colsoft_comb(const float* __restrict__ pmax, const float* __restrict__ psum,
                  float* __restrict__ cmax, float* __restrict__ cinv)
{
  const int d = blockIdx.x * 256 + threadIdx.x;
  const int b = blockIdx.y;
  float M = -3.0e38f;
#pragma unroll
  for (int c = 0; c < 16; ++c) M = fmaxf(M, pmax[((long)b * 16 + c) * D_ + d]);
  float s = 0.f;
#pragma unroll
  for (int c = 0; c < 16; ++c) {
    const long o = ((long)b * 16 + c) * D_ + d;
    s += psum[o] * __expf(pmax[o] - M);
  }
  cmax[(long)b * D_ + d] = M;
  cinv[(long)b * D_ + d] = 1.f / s;
}

// pass 3: normalize bf16 in place. grid: ((T_*D_)/2048, B_); 8 elems/thread.
__global__ __launch_bounds__(256)
void colsoft_norm(ushort* __restrict__ S, const float* __restrict__ cmax,
                  const float* __restrict__ cinv)
{
  const int b = blockIdx.y;
  const long i8 = (long)blockIdx.x * 256 + threadIdx.x;
  const long base = (long)b * T_ * D_ + i8 * 8;
  const int d = (int)((i8 * 8) & (D_ - 1));
  bf16x8 x = *(const bf16x8*)(S + base);
  const float4 m0 = *(const float4*)(cmax + (long)b * D_ + d);
  const float4 m1 = *(const float4*)(cmax + (long)b * D_ + d + 4);
  const float4 i0 = *(const float4*)(cinv + (long)b * D_ + d);
  const float4 i1 = *(const float4*)(cinv + (long)b * D_ + d + 4);
  const float mm[8] = {m0.x, m0.y, m0.z, m0.w, m1.x, m1.y, m1.z, m1.w};
  const float ii[8] = {i0.x, i0.y, i0.z, i0.w, i1.x, i1.y, i1.z, i1.w};
  bf16x8 o;
#pragma unroll
  for (int j = 0; j < 8; ++j)
    o[j] = (short)f2bf(__expf(bf2f((ushort)x[j]) - mm[j]) * ii[j]);
  *(bf16x8*)(S + base) = o;
}

extern "C" void kernel_launch(void* const* d_in, const int* in_sizes, int n_in,
                              void* d_out, int out_size, void* d_ws, size_t ws_size,
                              hipStream_t stream)
{
  (void)in_sizes; (void)n_in; (void)out_size; (void)ws_size;
  // ALL inputs are fp32 (reference dtypes). Output fp32.
  const float* lat = (const float*)d_in[0];   // [B,Tq,D]
  const float* inp = (const float*)d_in[1];   // [B,Tkv,D]
  const float* Wl  = (const float*)d_in[2];
  const float* bl  = (const float*)d_in[3];
  const float* Wu  = (const float*)d_in[4];
  const float* bu  = (const float*)d_in[5];
  const float* WA  = (const float*)d_in[6];
  const float* bA  = (const float*)d_in[7];
  const float* WV  = (const float*)d_in[8];
  const float* bV  = (const float*)d_in[9];
  const float* Wo  = (const float*)d_in[10];
  const float* bo  = (const float*)d_in[11];

  // Workspace (~58.6 MB):
  //   xBf   (16MB bf16): latent_bf16, later input_bf16
  //   wBf   ( 2MB bf16): current weight, converted just-in-time
  //   bufA  (16MB bf16): emb0 -> ov -> Dm
  //   bufB  (16MB bf16): S1 -> l (in place) -> S2 -> A (in place)
  //   MT    ( 8MB bf16)
  //   partials (~0.53MB fp32)
  char* w = (char*)d_ws;
  auto carve = [&](size_t bytes) { char* p = w; w += (bytes + 255) & ~(size_t)255; return p; };
  const long NT = (long)B_ * T_ * D_;                       // 8,388,608
  const long NW = (long)D_ * D_;                            // 1,048,576
  ushort* xBf  = (ushort*)carve(NT * 2);
  ushort* wBf  = (ushort*)carve(NW * 2);
  ushort* bufA = (ushort*)carve(NT * 2);
  ushort* bufB = (ushort*)carve(NT * 2);
  ushort* MT   = (ushort*)carve((long)B_ * D_ * D_ * 2);
  float*  pmax = (float*)carve((long)B_ * 16 * D_ * 4);
  float*  psum = (float*)carve((long)B_ * 16 * D_ * 4);
  float*  cmax = (float*)carve((long)B_ * D_ * 4);
  float*  cinv = (float*)carve((long)B_ * D_ * 4);

  const dim3 blk(256, 1, 1);
  const dim3 gBig(D_ / BN, (B_ * T_) / BM, 1);              // 8 x 64 tiles, batch fused in rows
  const int gCvtBig = (int)(NT / 4 / 256);                  // 8192
  const int gCvtW   = (int)(NW / 4 / 256);                  // 1024

  // latent -> bf16
  cvt_f32_bf16<<<dim3(gCvtBig), blk, 0, stream>>>(lat, xBf, NT / 4);
  // 1. emb0 = latent @ Wl^T + bl
  cvt_f32_bf16<<<dim3(gCvtW), blk, 0, stream>>>(Wl, wBf, NW / 4);
  gemm_nt<false, true><<<gBig, blk, 0, stream>>>(xBf, wBf, bl, bufA, D_, D_, 0, 0, 0);
  // 2. S1 = emb0 @ Wu^T + bu
  cvt_f32_bf16<<<dim3(gCvtW), blk, 0, stream>>>(Wu, wBf, NW / 4);
  gemm_nt<false, true><<<gBig, blk, 0, stream>>>(bufA, wBf, bu, bufB, D_, D_, 0, 0, 0);
  // 3. l = row-softmax(S1) in place
  softmax_row<<<dim3(B_ * T_), blk, 0, stream>>>(bufB, bufB);
  // 4. ov = latent @ Wo^T + bo    (bufA: emb0 dead)
  cvt_f32_bf16<<<dim3(gCvtW), blk, 0, stream>>>(Wo, wBf, NW / 4);
  gemm_nt<false, true><<<gBig, blk, 0, stream>>>(xBf, wBf, bo, bufA, D_, D_, 0, 0, 0);
  // 5. MT[b,d,e] = sum_q ov[b,q,d] * l[b,q,e]
  gemm_tn<<<dim3(D_ / BN, D_ / BM, B_), blk, 0, stream>>>(
      bufA, bufB, MT, D_, T_, D_, D_,
      (long)T_ * D_, (long)T_ * D_, (long)D_ * D_);
  // input -> bf16 (latent dead now)
  cvt_f32_bf16<<<dim3(gCvtBig), blk, 0, stream>>>(inp, xBf, NT / 4);
  // 6. Dm = input @ WA^T + bA     (bufA: ov dead)
  cvt_f32_bf16<<<dim3(gCvtW), blk, 0, stream>>>(WA, wBf, NW / 4);
  gemm_nt<false, true><<<gBig, blk, 0, stream>>>(xBf, wBf, bA, bufA, D_, D_, 0, 0, 0);
  // 7. S2 = Dm @ WV^T + bV        (bufB: l dead)
  cvt_f32_bf16<<<dim3(gCvtW), blk, 0, stream>>>(WV, wBf, NW / 4);
  gemm_nt<false, true><<<gBig, blk, 0, stream>>>(bufA, wBf, bV, bufB, D_, D_, 0, 0, 0);
  // 8. A = softmax(S2, over T_kv) in place
  colsoft_part<<<dim3(D_ / 256, 16, B_), blk, 0, stream>>>(bufB, pmax, psum);
  colsoft_comb<<<dim3(D_ / 256, B_, 1), blk, 0, stream>>>(pmax, psum, cmax, cinv);
  colsoft_norm<<<dim3((T_ * D_) / 2048, B_, 1), blk, 0, stream>>>(bufB, cmax, cinv);
  // 9. o[b,k,d] = sum_e A[b,k,e] * MT[b,d,e]  -> d_out (fp32)
  gemm_nt<true, false><<<dim3(D_ / BN, T_ / BM, B_), blk, 0, stream>>>(
      bufB, MT, nullptr, d_out, D_, D_,
      (long)T_ * D_, (long)D_ * D_, (long)T_ * D_);
}

// Round 4
// 440.024 us; speedup vs baseline: 1.2073x; 1.2073x over previous
//
#include <hip/hip_runtime.h>
#include <hip/hip_bf16.h>
#include <stdint.h>

typedef __attribute__((ext_vector_type(8))) short bf16x8;
typedef __attribute__((ext_vector_type(4))) float f32x4;
typedef __attribute__((ext_vector_type(4))) unsigned short u16x4;

#define B_  4
#define T_  2048
#define D_  1024
#define BM  128
#define BN  128
#define BK  32

__device__ __forceinline__ float bf2f(ushort u) {
  union { unsigned int i; float f; } v; v.i = ((unsigned int)u) << 16; return v.f;
}
__device__ __forceinline__ ushort f2bf(float f) {
  return (ushort)(__bfloat16_as_ushort(__float2bfloat16(f)));
}

__device__ __forceinline__ void async16(const void* g, void* l) {
  __builtin_amdgcn_global_load_lds(
      (const __attribute__((address_space(1))) void*)g,
      (__attribute__((address_space(3))) void*)l, 16, 0, 0);
}

// chunk swizzle: spreads the 4 16B chunks of a 64B k-row across banks by row
__device__ __forceinline__ int swz4(int r) { return (r ^ (r >> 2)) & 3; }

// fp32 -> bf16 convert, 4 elems/thread.
__global__ __launch_bounds__(256)
void cvt_f32_bf16(const float* __restrict__ in, ushort* __restrict__ out, long n4)
{
  const long i = (long)blockIdx.x * 256 + threadIdx.x;
  if (i >= n4) return;
  const float4 v = *(const float4*)(in + i * 4);
  u16x4 o;
  o[0] = f2bf(v.x); o[1] = f2bf(v.y); o[2] = f2bf(v.z); o[3] = f2bf(v.w);
  *(u16x4*)(out + i * 4) = o;
}

// bf16 tiled transpose: in[R][C] -> out[C][R], batch via blockIdx.z.
// grid (C/64, R/64, B). Coalesced 8B global reads/writes; LDS pad 65 (<=2-way, free).
__global__ __launch_bounds__(256)
void transpose_bf16(const ushort* __restrict__ in, ushort* __restrict__ out, int R, int C)
{
  __shared__ alignas(16) ushort t[64 * 65];
  const long bofs = (long)blockIdx.z * R * C;
  const int c0 = blockIdx.x * 64, r0 = blockIdx.y * 64;
  const int tx = threadIdx.x & 15, ty = threadIdx.x >> 4;
#pragma unroll
  for (int i = 0; i < 4; ++i) {
    const int r = ty + i * 16;
    u16x4 v = *(const u16x4*)(in + bofs + (long)(r0 + r) * C + c0 + tx * 4);
#pragma unroll
    for (int c = 0; c < 4; ++c) t[(tx * 4 + c) * 65 + r] = v[c];
  }
  __syncthreads();
#pragma unroll
  for (int i = 0; i < 4; ++i) {
    const int c = ty + i * 16;
    u16x4 v;
#pragma unroll
    for (int j = 0; j < 4; ++j) v[j] = t[c * 65 + tx * 4 + j];
    *(u16x4*)(out + bofs + (long)(c0 + c) * R + r0 + tx * 4) = v;
  }
}

// fused fp32->bf16 convert + transpose: in fp32 [R][C] -> out bf16 [C][R]. batch=1.
__global__ __launch_bounds__(256)
void cvt_t_f32_bf16(const float* __restrict__ in, ushort* __restrict__ out, int R, int C)
{
  __shared__ alignas(16) ushort t[64 * 65];
  const int c0 = blockIdx.x * 64, r0 = blockIdx.y * 64;
  const int tx = threadIdx.x & 15, ty = threadIdx.x >> 4;
#pragma unroll
  for (int i = 0; i < 4; ++i) {
    const int r = ty + i * 16;
    const float4 v = *(const float4*)(in + (long)(r0 + r) * C + c0 + tx * 4);
    t[(tx * 4 + 0) * 65 + r] = f2bf(v.x);
    t[(tx * 4 + 1) * 65 + r] = f2bf(v.y);
    t[(tx * 4 + 2) * 65 + r] = f2bf(v.z);
    t[(tx * 4 + 3) * 65 + r] = f2bf(v.w);
  }
  __syncthreads();
#pragma unroll
  for (int i = 0; i < 4; ++i) {
    const int c = ty + i * 16;
    u16x4 v;
#pragma unroll
    for (int j = 0; j < 4; ++j) v[j] = t[c * 65 + tx * 4 + j];
    *(u16x4*)(out + (long)(c0 + c) * R + r0 + tx * 4) = v;
  }
}

// bc[e] = sum_a W[e,a]*bin[a] + badd[e], all fp32. One wave per e.
__global__ __launch_bounds__(256)
void bias_comb(const float* __restrict__ W, const float* __restrict__ bin,
               const float* __restrict__ badd, float* __restrict__ out)
{
  const int wv = threadIdx.x >> 6, lane = threadIdx.x & 63;
  const int e = blockIdx.x * 4 + wv;
  const float* row = W + (long)e * D_;
  float s = 0.f;
#pragma unroll
  for (int i = 0; i < 16; ++i) s += row[lane + i * 64] * bin[lane + i * 64];
#pragma unroll
  for (int off = 32; off; off >>= 1) s += __shfl_xor(s, off);
  if (lane == 0) out[e] = s + badd[e];
}

// C[m,n] = sum_k A[m,k]*B[n,k] (+ bias[n]); A:[M,K] k-contig, B:[N,K] k-contig.
// ldc == N. Batched via blockIdx.z with element strides sA/sB/sC.
template<bool OUT_F32, bool HAS_BIAS>
__global__ __launch_bounds__(256, 2)
void gemm_nt(const ushort* __restrict__ A, const ushort* __restrict__ B,
             const float* __restrict__ bias, void* __restrict__ C,
             int N, int K, long sA, long sB, long sC)
{
  __shared__ alignas(16) ushort As[BM * BK];
  __shared__ alignas(16) ushort Bs[BN * BK];
  const int tid  = threadIdx.x;
  const int wave = tid >> 6;
  const int lane = tid & 63;
  const int wm   = wave >> 1;
  const int wn   = wave & 1;
  const int bz   = blockIdx.z;
  const int tileN = blockIdx.x * BN;
  const int tileM = blockIdx.y * BM;
  A += (long)bz * sA;
  B += (long)bz * sB;

  const int lrow   = lane >> 2;
  const int lchunk = (lane & 3) ^ swz4(lrow);

  f32x4 acc[4][4];
#pragma unroll
  for (int i = 0; i < 4; ++i)
#pragma unroll
    for (int j = 0; j < 4; ++j) acc[i][j] = (f32x4){0.f, 0.f, 0.f, 0.f};

  const int frow = lane & 15;
  const int kg   = lane >> 4;
  const int coff = ((kg ^ swz4(frow)) << 3);

  for (int kt = 0; kt < K; kt += BK) {
    __syncthreads();
#pragma unroll
    for (int i = 0; i < 2; ++i) {
      const int rg  = wave * 2 + i;
      const int row = rg * 16 + lrow;
      async16(A + (long)(tileM + row) * K + kt + lchunk * 8, (void*)(As + rg * 16 * BK));
      async16(B + (long)(tileN + row) * K + kt + lchunk * 8, (void*)(Bs + rg * 16 * BK));
    }
    __syncthreads();
    bf16x8 af[4], bfr[4];
#pragma unroll
    for (int mi = 0; mi < 4; ++mi)
      af[mi] = *(const bf16x8*)(As + (wm * 64 + mi * 16 + frow) * BK + coff);
#pragma unroll
    for (int ni = 0; ni < 4; ++ni)
      bfr[ni] = *(const bf16x8*)(Bs + (wn * 64 + ni * 16 + frow) * BK + coff);
#pragma unroll
    for (int mi = 0; mi < 4; ++mi)
#pragma unroll
      for (int ni = 0; ni < 4; ++ni)
        acc[mi][ni] = __builtin_amdgcn_mfma_f32_16x16x32_bf16(af[mi], bfr[ni], acc[mi][ni], 0, 0, 0);
  }

  const int rowbase = tileM + wm * 64 + ((lane >> 4) << 2);
  const int colbase = tileN + wn * 64 + (lane & 15);
#pragma unroll
  for (int ni = 0; ni < 4; ++ni) {
    const int col = colbase + ni * 16;
    float bv = 0.f;
    if constexpr (HAS_BIAS) bv = bias[col];
#pragma unroll
    for (int mi = 0; mi < 4; ++mi) {
#pragma unroll
      for (int r = 0; r < 4; ++r) {
        const int row = rowbase + mi * 16 + r;
        const float v = acc[mi][ni][r] + bv;
        const long idx = (long)bz * sC + (long)row * N + col;
        if constexpr (OUT_F32) ((float*)C)[idx] = v;
        else ((ushort*)C)[idx] = f2bf(v);
      }
    }
  }
}

// row softmax over last dim (D_=1024), bf16 in/out, in-place safe.
__global__ __launch_bounds__(256)
void softmax_row(const ushort* __restrict__ S, ushort* __restrict__ O)
{
  const long base = (long)blockIdx.x * D_;
  const int tid = threadIdx.x;
  float v[4];
#pragma unroll
  for (int i = 0; i < 4; ++i) v[i] = bf2f(S[base + i * 256 + tid]);
  float m = fmaxf(fmaxf(v[0], v[1]), fmaxf(v[2], v[3]));
#pragma unroll
  for (int off = 32; off; off >>= 1) m = fmaxf(m, __shfl_xor(m, off));
  __shared__ float redm[4], reds[4];
  const int wv = tid >> 6;
  if ((tid & 63) == 0) redm[wv] = m;
  __syncthreads();
  m = fmaxf(fmaxf(redm[0], redm[1]), fmaxf(redm[2], redm[3]));
  float e[4], s = 0.f;
#pragma unroll
  for (int i = 0; i < 4; ++i) { e[i] = __expf(v[i] - m); s += e[i]; }
#pragma unroll
  for (int off = 32; off; off >>= 1) s += __shfl_xor(s, off);
  if ((tid & 63) == 0) reds[wv] = s;
  __syncthreads();
  s = reds[0] + reds[1] + reds[2] + reds[3];
  const float inv = 1.f / s;
#pragma unroll
  for (int i = 0; i < 4; ++i)
    O[base + i * 256 + tid] = f2bf(e[i] * inv);
}

// column softmax pass 1: per-chunk online max/sum. grid (D_/256, 16, B_).
__global__ __launch_bounds__(256)
void colsoft_part(const ushort* __restrict__ S, float* __restrict__ pmax, float* __restrict__ psum)
{
  const int d = blockIdx.x * 256 + threadIdx.x;
  const int c = blockIdx.y;
  const int b = blockIdx.z;
  const ushort* p = S + ((long)b * T_ + (long)c * 128) * D_ + d;
  float m = -3.0e38f, s = 0.f;
#pragma unroll 4
  for (int r = 0; r < 128; ++r) {
    const float x = bf2f(p[(long)r * D_]);
    if (x > m) { s = s * __expf(m - x) + 1.f; m = x; }
    else       { s += __expf(x - m); }
  }
  const long o = ((long)b * 16 + c) * D_ + d;
  pmax[o] = m;
  psum[o] = s;
}

// pass 2: combine partials. grid (D_/256, B_).
__global__ __launch_bounds__(256)
void colsoft_comb(const float* __restrict__ pmax, const float* __restrict__ psum,
                  float* __restrict__ cmax, float* __restrict__ cinv)
{
  const int d = blockIdx.x * 256 + threadIdx.x;
  const int b = blockIdx.y;
  float M = -3.0e38f;
#pragma unroll
  for (int c = 0; c < 16; ++c) M = fmaxf(M, pmax[((long)b * 16 + c) * D_ + d]);
  float s = 0.f;
#pragma unroll
  for (int c = 0; c < 16; ++c) {
    const long o = ((long)b * 16 + c) * D_ + d;
    s += psum[o] * __expf(pmax[o] - M);
  }
  cmax[(long)b * D_ + d] = M;
  cinv[(long)b * D_ + d] = 1.f / s;
}

// pass 3: normalize bf16 in place. grid ((T_*D_)/2048, B_).
__global__ __launch_bounds__(256)
void colsoft_norm(ushort* __restrict__ S, const float* __restrict__ cmax,
                  const float* __restrict__ cinv)
{
  const int b = blockIdx.y;
  const long i8 = (long)blockIdx.x * 256 + threadIdx.x;
  const long base = (long)b * T_ * D_ + i8 * 8;
  const int d = (int)((i8 * 8) & (D_ - 1));
  bf16x8 x = *(const bf16x8*)(S + base);
  const float4 m0 = *(const float4*)(cmax + (long)b * D_ + d);
  const float4 m1 = *(const float4*)(cmax + (long)b * D_ + d + 4);
  const float4 i0 = *(const float4*)(cinv + (long)b * D_ + d);
  const float4 i1 = *(const float4*)(cinv + (long)b * D_ + d + 4);
  const float mm[8] = {m0.x, m0.y, m0.z, m0.w, m1.x, m1.y, m1.z, m1.w};
  const float ii[8] = {i0.x, i0.y, i0.z, i0.w, i1.x, i1.y, i1.z, i1.w};
  bf16x8 o;
#pragma unroll
  for (int j = 0; j < 8; ++j)
    o[j] = (short)f2bf(__expf(bf2f((ushort)x[j]) - mm[j]) * ii[j]);
  *(bf16x8*)(S + base) = o;
}

extern "C" void kernel_launch(void* const* d_in, const int* in_sizes, int n_in,
                              void* d_out, int out_size, void* d_ws, size_t ws_size,
                              hipStream_t stream)
{
  (void)in_sizes; (void)n_in; (void)out_size; (void)ws_size;
  const float* lat = (const float*)d_in[0];
  const float* inp = (const float*)d_in[1];
  const float* Wl  = (const float*)d_in[2];
  const float* bl  = (const float*)d_in[3];
  const float* Wu  = (const float*)d_in[4];
  const float* bu  = (const float*)d_in[5];
  const float* WA  = (const float*)d_in[6];
  const float* bA  = (const float*)d_in[7];
  const float* WV  = (const float*)d_in[8];
  const float* bV  = (const float*)d_in[9];
  const float* Wo  = (const float*)d_in[10];
  const float* bo  = (const float*)d_in[11];

  // Workspace (~62.6 MB):
  //   xBf  (16MB): latent_bf16 -> lT -> input_bf16
  //   bufA (16MB): ov
  //   bufB (16MB): S1 -> l (in place) -> ovT -> S2 -> A (in place)
  //   MT   ( 8MB)
  //   w1,w2,w3 (2MB each), bc/bc2 (4KB each), partials (~0.53MB)
  char* w = (char*)d_ws;
  auto carve = [&](size_t bytes) { char* p = w; w += (bytes + 255) & ~(size_t)255; return p; };
  const long NT = (long)B_ * T_ * D_;
  const long NW = (long)D_ * D_;
  ushort* xBf  = (ushort*)carve(NT * 2);
  ushort* bufA = (ushort*)carve(NT * 2);
  ushort* bufB = (ushort*)carve(NT * 2);
  ushort* MT   = (ushort*)carve((long)B_ * D_ * D_ * 2);
  ushort* w1   = (ushort*)carve(NW * 2);
  ushort* w2   = (ushort*)carve(NW * 2);
  ushort* w3   = (ushort*)carve(NW * 2);
  float*  bc   = (float*)carve(D_ * 4);
  float*  bc2  = (float*)carve(D_ * 4);
  float*  pmax = (float*)carve((long)B_ * 16 * D_ * 4);
  float*  psum = (float*)carve((long)B_ * 16 * D_ * 4);
  float*  cmax = (float*)carve((long)B_ * D_ * 4);
  float*  cinv = (float*)carve((long)B_ * D_ * 4);

  const dim3 blk(256, 1, 1);
  const dim3 gBig(D_ / BN, (B_ * T_) / BM, 1);   // 8 x 64
  const dim3 gW(D_ / BN, D_ / BM, 1);            // 8 x 8
  const int gCvtBig = (int)(NT / 4 / 256);
  const int gCvtW   = (int)(NW / 4 / 256);

  // latent -> bf16
  cvt_f32_bf16<<<dim3(gCvtBig), blk, 0, stream>>>(lat, xBf, NT / 4);
  // Wc = Wu · Wl  (S1 = lat @ Wc^T + bc):  w1=Wu_bf, w2=Wl^T_bf, w3=Wc
  cvt_f32_bf16<<<dim3(gCvtW), blk, 0, stream>>>(Wu, w1, NW / 4);
  cvt_t_f32_bf16<<<dim3(16, 16, 1), blk, 0, stream>>>(Wl, w2, D_, D_);
  gemm_nt<false, false><<<gW, blk, 0, stream>>>(w1, w2, nullptr, w3, D_, D_, 0, 0, 0);
  bias_comb<<<dim3(D_ / 4), blk, 0, stream>>>(Wu, bl, bu, bc);
  // S1 = lat @ Wc^T + bc -> bufB
  gemm_nt<false, true><<<gBig, blk, 0, stream>>>(xBf, w3, bc, bufB, D_, D_, 0, 0, 0);
  // l = row-softmax(S1) in place
  softmax_row<<<dim3(B_ * T_), blk, 0, stream>>>(bufB, bufB);
  // ov = lat @ Wo^T + bo -> bufA
  cvt_f32_bf16<<<dim3(gCvtW), blk, 0, stream>>>(Wo, w1, NW / 4);
  gemm_nt<false, true><<<gBig, blk, 0, stream>>>(xBf, w1, bo, bufA, D_, D_, 0, 0, 0);
  // lT: l[q,e] -> lT[e,q] into xBf (latent dead)
  transpose_bf16<<<dim3(D_ / 64, T_ / 64, B_), blk, 0, stream>>>(bufB, xBf, T_, D_);
  // ovT: ov[q,d] -> ovT[d,q] into bufB (l dead)
  transpose_bf16<<<dim3(D_ / 64, T_ / 64, B_), blk, 0, stream>>>(bufA, bufB, T_, D_);
  // MT[d,e] = sum_q ovT[d,q] * lT[e,q]   (NT, K=2048)
  gemm_nt<false, false><<<dim3(D_ / BN, D_ / BM, B_), blk, 0, stream>>>(
      bufB, xBf, nullptr, MT, D_, T_,
      (long)D_ * T_, (long)D_ * T_, (long)D_ * D_);
  // input -> bf16 (lT dead)
  cvt_f32_bf16<<<dim3(gCvtBig), blk, 0, stream>>>(inp, xBf, NT / 4);
  // Wc2 = WV · WA  (S2 = inp @ Wc2^T + bc2)
  cvt_f32_bf16<<<dim3(gCvtW), blk, 0, stream>>>(WV, w1, NW / 4);
  cvt_t_f32_bf16<<<dim3(16, 16, 1), blk, 0, stream>>>(WA, w2, D_, D_);
  gemm_nt<false, false><<<gW, blk, 0, stream>>>(w1, w2, nullptr, w3, D_, D_, 0, 0, 0);
  bias_comb<<<dim3(D_ / 4), blk, 0, stream>>>(WV, bA, bV, bc2);
  // S2 = inp @ Wc2^T + bc2 -> bufB (ovT dead)
  gemm_nt<false, true><<<gBig, blk, 0, stream>>>(xBf, w3, bc2, bufB, D_, D_, 0, 0, 0);
  // A = softmax over T_kv, in place
  colsoft_part<<<dim3(D_ / 256, 16, B_), blk, 0, stream>>>(bufB, pmax, psum);
  colsoft_comb<<<dim3(D_ / 256, B_, 1), blk, 0, stream>>>(pmax, psum, cmax, cinv);
  colsoft_norm<<<dim3((T_ * D_) / 2048, B_, 1), blk, 0, stream>>>(bufB, cmax, cinv);
  // o = A @ MT^T -> d_out (fp32)
  gemm_nt<true, false><<<dim3(D_ / BN, T_ / BM, B_), blk, 0, stream>>>(
      bufB, MT, nullptr, d_out, D_, D_,
      (long)T_ * D_, (long)D_ * D_, (long)T_ * D_);
}

// Round 5
// 397.362 us; speedup vs baseline: 1.3369x; 1.1074x over previous
//
#include <hip/hip_runtime.h>
#include <hip/hip_bf16.h>
#include <stdint.h>

typedef __attribute__((ext_vector_type(8))) short bf16x8;
typedef __attribute__((ext_vector_type(4))) float f32x4;
typedef __attribute__((ext_vector_type(4))) unsigned short u16x4;

#define B_  4
#define T_  2048
#define D_  1024
#define BM  128
#define BN  128
#define BK  32

__device__ __forceinline__ float bf2f(ushort u) {
  union { unsigned int i; float f; } v; v.i = ((unsigned int)u) << 16; return v.f;
}
__device__ __forceinline__ ushort f2bf(float f) {
  return (ushort)(__bfloat16_as_ushort(__float2bfloat16(f)));
}

__device__ __forceinline__ void async16(const void* g, void* l) {
  __builtin_amdgcn_global_load_lds(
      (const __attribute__((address_space(1))) void*)g,
      (__attribute__((address_space(3))) void*)l, 16, 0, 0);
}

__device__ __forceinline__ int swz4(int r) { return (r ^ (r >> 2)) & 3; }

// ---------------- converts ----------------
__global__ __launch_bounds__(256)
void cvt_f32_bf16(const float* __restrict__ in, ushort* __restrict__ out, long n4)
{
  const long i = (long)blockIdx.x * 256 + threadIdx.x;
  if (i >= n4) return;
  const float4 v = *(const float4*)(in + i * 4);
  u16x4 o;
  o[0] = f2bf(v.x); o[1] = f2bf(v.y); o[2] = f2bf(v.z); o[3] = f2bf(v.w);
  *(u16x4*)(out + i * 4) = o;
}

// two tensors in one launch (blockIdx.y selects)
__global__ __launch_bounds__(256)
void cvt2_f32_bf16(const float* __restrict__ in0, ushort* __restrict__ out0,
                   const float* __restrict__ in1, ushort* __restrict__ out1, long n4)
{
  const float* in  = blockIdx.y ? in1 : in0;
  ushort*      out = blockIdx.y ? out1 : out0;
  const long i = (long)blockIdx.x * 256 + threadIdx.x;
  if (i >= n4) return;
  const float4 v = *(const float4*)(in + i * 4);
  u16x4 o;
  o[0] = f2bf(v.x); o[1] = f2bf(v.y); o[2] = f2bf(v.z); o[3] = f2bf(v.w);
  *(u16x4*)(out + i * 4) = o;
}

// fused fp32->bf16 convert + transpose, two tensors via blockIdx.z. [R][C] -> [C][R]
__global__ __launch_bounds__(256)
void cvt_t2_f32_bf16(const float* __restrict__ in0, ushort* __restrict__ out0,
                     const float* __restrict__ in1, ushort* __restrict__ out1,
                     int R, int C)
{
  __shared__ alignas(16) ushort t[64 * 65];
  const float* in  = blockIdx.z ? in1 : in0;
  ushort*      out = blockIdx.z ? out1 : out0;
  const int c0 = blockIdx.x * 64, r0 = blockIdx.y * 64;
  const int tx = threadIdx.x & 15, ty = threadIdx.x >> 4;
#pragma unroll
  for (int i = 0; i < 4; ++i) {
    const int r = ty + i * 16;
    const float4 v = *(const float4*)(in + (long)(r0 + r) * C + c0 + tx * 4);
    t[(tx * 4 + 0) * 65 + r] = f2bf(v.x);
    t[(tx * 4 + 1) * 65 + r] = f2bf(v.y);
    t[(tx * 4 + 2) * 65 + r] = f2bf(v.z);
    t[(tx * 4 + 3) * 65 + r] = f2bf(v.w);
  }
  __syncthreads();
#pragma unroll
  for (int i = 0; i < 4; ++i) {
    const int c = ty + i * 16;
    u16x4 v;
#pragma unroll
    for (int j = 0; j < 4; ++j) v[j] = t[c * 65 + tx * 4 + j];
    *(u16x4*)(out + (long)(c0 + c) * R + r0 + tx * 4) = v;
  }
}

// bf16 tiled transpose: in[R][C] -> out[C][R], batch via blockIdx.z.
__global__ __launch_bounds__(256)
void transpose_bf16(const ushort* __restrict__ in, ushort* __restrict__ out, int R, int C)
{
  __shared__ alignas(16) ushort t[64 * 65];
  const long bofs = (long)blockIdx.z * R * C;
  const int c0 = blockIdx.x * 64, r0 = blockIdx.y * 64;
  const int tx = threadIdx.x & 15, ty = threadIdx.x >> 4;
#pragma unroll
  for (int i = 0; i < 4; ++i) {
    const int r = ty + i * 16;
    u16x4 v = *(const u16x4*)(in + bofs + (long)(r0 + r) * C + c0 + tx * 4);
#pragma unroll
    for (int c = 0; c < 4; ++c) t[(tx * 4 + c) * 65 + r] = v[c];
  }
  __syncthreads();
#pragma unroll
  for (int i = 0; i < 4; ++i) {
    const int c = ty + i * 16;
    u16x4 v;
#pragma unroll
    for (int j = 0; j < 4; ++j) v[j] = t[c * 65 + tx * 4 + j];
    *(u16x4*)(out + bofs + (long)(c0 + c) * R + r0 + tx * 4) = v;
  }
}

// bc[e] = sum_a W[e,a]*bin[a] + badd[e], fp32. Two problem-sets via blockIdx.y.
__global__ __launch_bounds__(256)
void bias_comb2(const float* __restrict__ W0, const float* __restrict__ bin0,
                const float* __restrict__ badd0, float* __restrict__ out0,
                const float* __restrict__ W1, const float* __restrict__ bin1,
                const float* __restrict__ badd1, float* __restrict__ out1)
{
  const float* W    = blockIdx.y ? W1 : W0;
  const float* bin  = blockIdx.y ? bin1 : bin0;
  const float* badd = blockIdx.y ? badd1 : badd0;
  float*       out  = blockIdx.y ? out1 : out0;
  const int wv = threadIdx.x >> 6, lane = threadIdx.x & 63;
  const int e = blockIdx.x * 4 + wv;
  const float* row = W + (long)e * D_;
  float s = 0.f;
#pragma unroll
  for (int i = 0; i < 16; ++i) s += row[lane + i * 64] * bin[lane + i * 64];
#pragma unroll
  for (int off = 32; off; off >>= 1) s += __shfl_xor(s, off);
  if (lane == 0) out[e] = s + badd[e];
}

// ---------------- GEMMs ----------------
// C[m,n] = sum_k A[m,k]*B[n,k] (+ bias[n]); batched via blockIdx.z.
template<bool OUT_F32, bool HAS_BIAS>
__global__ __launch_bounds__(256, 2)
void gemm_nt(const ushort* __restrict__ A, const ushort* __restrict__ B,
             const float* __restrict__ bias, void* __restrict__ C,
             int N, int K, long sA, long sB, long sC)
{
  __shared__ alignas(16) ushort As[BM * BK];
  __shared__ alignas(16) ushort Bs[BN * BK];
  const int tid  = threadIdx.x;
  const int wave = tid >> 6;
  const int lane = tid & 63;
  const int wm   = wave >> 1;
  const int wn   = wave & 1;
  const int bz   = blockIdx.z;
  const int tileN = blockIdx.x * BN;
  const int tileM = blockIdx.y * BM;
  A += (long)bz * sA;
  B += (long)bz * sB;

  const int lrow   = lane >> 2;
  const int lchunk = (lane & 3) ^ swz4(lrow);

  f32x4 acc[4][4];
#pragma unroll
  for (int i = 0; i < 4; ++i)
#pragma unroll
    for (int j = 0; j < 4; ++j) acc[i][j] = (f32x4){0.f, 0.f, 0.f, 0.f};

  const int frow = lane & 15;
  const int kg   = lane >> 4;
  const int coff = ((kg ^ swz4(frow)) << 3);

  for (int kt = 0; kt < K; kt += BK) {
    __syncthreads();
#pragma unroll
    for (int i = 0; i < 2; ++i) {
      const int rg  = wave * 2 + i;
      const int row = rg * 16 + lrow;
      async16(A + (long)(tileM + row) * K + kt + lchunk * 8, (void*)(As + rg * 16 * BK));
      async16(B + (long)(tileN + row) * K + kt + lchunk * 8, (void*)(Bs + rg * 16 * BK));
    }
    __syncthreads();
    bf16x8 af[4], bfr[4];
#pragma unroll
    for (int mi = 0; mi < 4; ++mi)
      af[mi] = *(const bf16x8*)(As + (wm * 64 + mi * 16 + frow) * BK + coff);
#pragma unroll
    for (int ni = 0; ni < 4; ++ni)
      bfr[ni] = *(const bf16x8*)(Bs + (wn * 64 + ni * 16 + frow) * BK + coff);
#pragma unroll
    for (int mi = 0; mi < 4; ++mi)
#pragma unroll
      for (int ni = 0; ni < 4; ++ni)
        acc[mi][ni] = __builtin_amdgcn_mfma_f32_16x16x32_bf16(af[mi], bfr[ni], acc[mi][ni], 0, 0, 0);
  }

  const int rowbase = tileM + wm * 64 + ((lane >> 4) << 2);
  const int colbase = tileN + wn * 64 + (lane & 15);
#pragma unroll
  for (int ni = 0; ni < 4; ++ni) {
    const int col = colbase + ni * 16;
    float bv = 0.f;
    if constexpr (HAS_BIAS) bv = bias[col];
#pragma unroll
    for (int mi = 0; mi < 4; ++mi) {
#pragma unroll
      for (int r = 0; r < 4; ++r) {
        const int row = rowbase + mi * 16 + r;
        const float v = acc[mi][ni][r] + bv;
        const long idx = (long)bz * sC + (long)row * N + col;
        if constexpr (OUT_F32) ((float*)C)[idx] = v;
        else ((ushort*)C)[idx] = f2bf(v);
      }
    }
  }
}

// Dual-output GEMM: B is [2048, K] = [Wc ; Wo]. tileN < 1024 -> C1/bias1, else C2/bias2.
// Both outputs [M, 1024] bf16.
__global__ __launch_bounds__(256, 2)
void gemm_nt_dual(const ushort* __restrict__ A, const ushort* __restrict__ B,
                  const float* __restrict__ bias1, const float* __restrict__ bias2,
                  ushort* __restrict__ C1, ushort* __restrict__ C2, int K)
{
  __shared__ alignas(16) ushort As[BM * BK];
  __shared__ alignas(16) ushort Bs[BN * BK];
  const int tid  = threadIdx.x;
  const int wave = tid >> 6;
  const int lane = tid & 63;
  const int wm   = wave >> 1;
  const int wn   = wave & 1;
  const int tileN = blockIdx.x * BN;        // 0..2047
  const int tileM = blockIdx.y * BM;
  const bool second = tileN >= D_;
  ushort* C = second ? C2 : C1;
  const float* bias = second ? bias2 : bias1;
  const int colOfs = second ? D_ : 0;

  const int lrow   = lane >> 2;
  const int lchunk = (lane & 3) ^ swz4(lrow);

  f32x4 acc[4][4];
#pragma unroll
  for (int i = 0; i < 4; ++i)
#pragma unroll
    for (int j = 0; j < 4; ++j) acc[i][j] = (f32x4){0.f, 0.f, 0.f, 0.f};

  const int frow = lane & 15;
  const int kg   = lane >> 4;
  const int coff = ((kg ^ swz4(frow)) << 3);

  for (int kt = 0; kt < K; kt += BK) {
    __syncthreads();
#pragma unroll
    for (int i = 0; i < 2; ++i) {
      const int rg  = wave * 2 + i;
      const int row = rg * 16 + lrow;
      async16(A + (long)(tileM + row) * K + kt + lchunk * 8, (void*)(As + rg * 16 * BK));
      async16(B + (long)(tileN + row) * K + kt + lchunk * 8, (void*)(Bs + rg * 16 * BK));
    }
    __syncthreads();
    bf16x8 af[4], bfr[4];
#pragma unroll
    for (int mi = 0; mi < 4; ++mi)
      af[mi] = *(const bf16x8*)(As + (wm * 64 + mi * 16 + frow) * BK + coff);
#pragma unroll
    for (int ni = 0; ni < 4; ++ni)
      bfr[ni] = *(const bf16x8*)(Bs + (wn * 64 + ni * 16 + frow) * BK + coff);
#pragma unroll
    for (int mi = 0; mi < 4; ++mi)
#pragma unroll
      for (int ni = 0; ni < 4; ++ni)
        acc[mi][ni] = __builtin_amdgcn_mfma_f32_16x16x32_bf16(af[mi], bfr[ni], acc[mi][ni], 0, 0, 0);
  }

  const int rowbase = tileM + wm * 64 + ((lane >> 4) << 2);
  const int colbase = tileN - colOfs + wn * 64 + (lane & 15);
#pragma unroll
  for (int ni = 0; ni < 4; ++ni) {
    const int col = colbase + ni * 16;
    const float bv = bias[col];
#pragma unroll
    for (int mi = 0; mi < 4; ++mi) {
#pragma unroll
      for (int r = 0; r < 4; ++r) {
        const int row = rowbase + mi * 16 + r;
        C[(long)row * D_ + col] = f2bf(acc[mi][ni][r] + bv);
      }
    }
  }
}

// Split-K NT GEMM for MT: z = bz*4 + split; each block does K=512 of 2048.
// Writes bf16 partials[split][bz][m][n], M=N=1024.
__global__ __launch_bounds__(256, 2)
void gemm_nt_splitk(const ushort* __restrict__ A, const ushort* __restrict__ B,
                    ushort* __restrict__ P)
{
  __shared__ alignas(16) ushort As[BM * BK];
  __shared__ alignas(16) ushort Bs[BN * BK];
  const int tid  = threadIdx.x;
  const int wave = tid >> 6;
  const int lane = tid & 63;
  const int wm   = wave >> 1;
  const int wn   = wave & 1;
  const int bz   = blockIdx.z >> 2;
  const int sp   = blockIdx.z & 3;
  const int tileN = blockIdx.x * BN;
  const int tileM = blockIdx.y * BM;
  const int kStart = sp * (T_ / 4);
  A += (long)bz * D_ * T_;
  B += (long)bz * D_ * T_;

  const int lrow   = lane >> 2;
  const int lchunk = (lane & 3) ^ swz4(lrow);

  f32x4 acc[4][4];
#pragma unroll
  for (int i = 0; i < 4; ++i)
#pragma unroll
    for (int j = 0; j < 4; ++j) acc[i][j] = (f32x4){0.f, 0.f, 0.f, 0.f};

  const int frow = lane & 15;
  const int kg   = lane >> 4;
  const int coff = ((kg ^ swz4(frow)) << 3);

  for (int kt = kStart; kt < kStart + T_ / 4; kt += BK) {
    __syncthreads();
#pragma unroll
    for (int i = 0; i < 2; ++i) {
      const int rg  = wave * 2 + i;
      const int row = rg * 16 + lrow;
      async16(A + (long)(tileM + row) * T_ + kt + lchunk * 8, (void*)(As + rg * 16 * BK));
      async16(B + (long)(tileN + row) * T_ + kt + lchunk * 8, (void*)(Bs + rg * 16 * BK));
    }
    __syncthreads();
    bf16x8 af[4], bfr[4];
#pragma unroll
    for (int mi = 0; mi < 4; ++mi)
      af[mi] = *(const bf16x8*)(As + (wm * 64 + mi * 16 + frow) * BK + coff);
#pragma unroll
    for (int ni = 0; ni < 4; ++ni)
      bfr[ni] = *(const bf16x8*)(Bs + (wn * 64 + ni * 16 + frow) * BK + coff);
#pragma unroll
    for (int mi = 0; mi < 4; ++mi)
#pragma unroll
      for (int ni = 0; ni < 4; ++ni)
        acc[mi][ni] = __builtin_amdgcn_mfma_f32_16x16x32_bf16(af[mi], bfr[ni], acc[mi][ni], 0, 0, 0);
  }

  ushort* C = P + ((long)sp * B_ + bz) * D_ * D_;
  const int rowbase = tileM + wm * 64 + ((lane >> 4) << 2);
  const int colbase = tileN + wn * 64 + (lane & 15);
#pragma unroll
  for (int ni = 0; ni < 4; ++ni) {
    const int col = colbase + ni * 16;
#pragma unroll
    for (int mi = 0; mi < 4; ++mi) {
#pragma unroll
      for (int r = 0; r < 4; ++r) {
        const int row = rowbase + mi * 16 + r;
        C[(long)row * D_ + col] = f2bf(acc[mi][ni][r]);
      }
    }
  }
}

// MT[i] = bf16(sum over 4 splits of partials), 8 elems/thread.
__global__ __launch_bounds__(256)
void reduce4_bf16(const ushort* __restrict__ P, ushort* __restrict__ MT)
{
  const long stride = (long)B_ * D_ * D_;
  const long base = ((long)blockIdx.x * 256 + threadIdx.x) * 8;
  bf16x8 p0 = *(const bf16x8*)(P + base);
  bf16x8 p1 = *(const bf16x8*)(P + stride + base);
  bf16x8 p2 = *(const bf16x8*)(P + 2 * stride + base);
  bf16x8 p3 = *(const bf16x8*)(P + 3 * stride + base);
  bf16x8 o;
#pragma unroll
  for (int j = 0; j < 8; ++j) {
    const float s = bf2f((ushort)p0[j]) + bf2f((ushort)p1[j]) +
                    bf2f((ushort)p2[j]) + bf2f((ushort)p3[j]);
    o[j] = (short)f2bf(s);
  }
  *(bf16x8*)(MT + base) = o;
}

// ---------------- softmaxes ----------------
__global__ __launch_bounds__(256)
void softmax_row(const ushort* __restrict__ S, ushort* __restrict__ O)
{
  const long base = (long)blockIdx.x * D_;
  const int tid = threadIdx.x;
  float v[4];
#pragma unroll
  for (int i = 0; i < 4; ++i) v[i] = bf2f(S[base + i * 256 + tid]);
  float m = fmaxf(fmaxf(v[0], v[1]), fmaxf(v[2], v[3]));
#pragma unroll
  for (int off = 32; off; off >>= 1) m = fmaxf(m, __shfl_xor(m, off));
  __shared__ float redm[4], reds[4];
  const int wv = tid >> 6;
  if ((tid & 63) == 0) redm[wv] = m;
  __syncthreads();
  m = fmaxf(fmaxf(redm[0], redm[1]), fmaxf(redm[2], redm[3]));
  float e[4], s = 0.f;
#pragma unroll
  for (int i = 0; i < 4; ++i) { e[i] = __expf(v[i] - m); s += e[i]; }
#pragma unroll
  for (int off = 32; off; off >>= 1) s += __shfl_xor(s, off);
  if ((tid & 63) == 0) reds[wv] = s;
  __syncthreads();
  s = reds[0] + reds[1] + reds[2] + reds[3];
  const float inv = 1.f / s;
#pragma unroll
  for (int i = 0; i < 4; ++i)
    O[base + i * 256 + tid] = f2bf(e[i] * inv);
}

__global__ __launch_bounds__(256)
void colsoft_part(const ushort* __restrict__ S, float* __restrict__ pmax, float* __restrict__ psum)
{
  const int d = blockIdx.x * 256 + threadIdx.x;
  const int c = blockIdx.y;
  const int b = blockIdx.z;
  const ushort* p = S + ((long)b * T_ + (long)c * 128) * D_ + d;
  float m = -3.0e38f, s = 0.f;
#pragma unroll 4
  for (int r = 0; r < 128; ++r) {
    const float x = bf2f(p[(long)r * D_]);
    if (x > m) { s = s * __expf(m - x) + 1.f; m = x; }
    else       { s += __expf(x - m); }
  }
  const long o = ((long)b * 16 + c) * D_ + d;
  pmax[o] = m;
  psum[o] = s;
}

__global__ __launch_bounds__(256)
void colsoft_comb(const float* __restrict__ pmax, const float* __restrict__ psum,
                  float* __restrict__ cmax, float* __restrict__ cinv)
{
  const int d = blockIdx.x * 256 + threadIdx.x;
  const int b = blockIdx.y;
  float M = -3.0e38f;
#pragma unroll
  for (int c = 0; c < 16; ++c) M = fmaxf(M, pmax[((long)b * 16 + c) * D_ + d]);
  float s = 0.f;
#pragma unroll
  for (int c = 0; c < 16; ++c) {
    const long o = ((long)b * 16 + c) * D_ + d;
    s += psum[o] * __expf(pmax[o] - M);
  }
  cmax[(long)b * D_ + d] = M;
  cinv[(long)b * D_ + d] = 1.f / s;
}

__global__ __launch_bounds__(256)
void colsoft_norm(ushort* __restrict__ S, const float* __restrict__ cmax,
                  const float* __restrict__ cinv)
{
  const int b = blockIdx.y;
  const long i8 = (long)blockIdx.x * 256 + threadIdx.x;
  const long base = (long)b * T_ * D_ + i8 * 8;
  const int d = (int)((i8 * 8) & (D_ - 1));
  bf16x8 x = *(const bf16x8*)(S + base);
  const float4 m0 = *(const float4*)(cmax + (long)b * D_ + d);
  const float4 m1 = *(const float4*)(cmax + (long)b * D_ + d + 4);
  const float4 i0 = *(const float4*)(cinv + (long)b * D_ + d);
  const float4 i1 = *(const float4*)(cinv + (long)b * D_ + d + 4);
  const float mm[8] = {m0.x, m0.y, m0.z, m0.w, m1.x, m1.y, m1.z, m1.w};
  const float ii[8] = {i0.x, i0.y, i0.z, i0.w, i1.x, i1.y, i1.z, i1.w};
  bf16x8 o;
#pragma unroll
  for (int j = 0; j < 8; ++j)
    o[j] = (short)f2bf(__expf(bf2f((ushort)x[j]) - mm[j]) * ii[j]);
  *(bf16x8*)(S + base) = o;
}

extern "C" void kernel_launch(void* const* d_in, const int* in_sizes, int n_in,
                              void* d_out, int out_size, void* d_ws, size_t ws_size,
                              hipStream_t stream)
{
  (void)in_sizes; (void)n_in; (void)out_size; (void)ws_size;
  const float* lat = (const float*)d_in[0];
  const float* inp = (const float*)d_in[1];
  const float* Wl  = (const float*)d_in[2];
  const float* bl  = (const float*)d_in[3];
  const float* Wu  = (const float*)d_in[4];
  const float* bu  = (const float*)d_in[5];
  const float* WA  = (const float*)d_in[6];
  const float* bA  = (const float*)d_in[7];
  const float* WV  = (const float*)d_in[8];
  const float* bV  = (const float*)d_in[9];
  const float* Wo  = (const float*)d_in[10];
  const float* bo  = (const float*)d_in[11];

  // Workspace (~99 MB):
  //   xBf  (16MB): latent_bf16 -> lT -> input_bf16
  //   bufA (16MB): ov
  //   bufB (16MB): S1 -> l (in place) -> ovT -> S2 -> A (in place)
  //   MT   ( 8MB)
  //   wCat ( 6MB): [Wc ; Wo_bf ; Wc2]  (rows 0..1023 / 1024..2047 / 2048..3071)
  //   w1   ( 4MB): [Wu_bf ; WV_bf]
  //   w2   ( 4MB): [WlT ; WAT]
  //   part (32MB): 4 bf16 split-K partials for MT
  //   bc/bc2/partials-of-softmax small
  char* w = (char*)d_ws;
  auto carve = [&](size_t bytes) { char* p = w; w += (bytes + 255) & ~(size_t)255; return p; };
  const long NT = (long)B_ * T_ * D_;
  const long NW = (long)D_ * D_;
  ushort* xBf  = (ushort*)carve(NT * 2);
  ushort* bufA = (ushort*)carve(NT * 2);
  ushort* bufB = (ushort*)carve(NT * 2);
  ushort* MT   = (ushort*)carve((long)B_ * D_ * D_ * 2);
  ushort* wCat = (ushort*)carve(3 * NW * 2);
  ushort* w1   = (ushort*)carve(2 * NW * 2);
  ushort* w2   = (ushort*)carve(2 * NW * 2);
  ushort* part = (ushort*)carve(4 * (long)B_ * D_ * D_ * 2);
  float*  bc   = (float*)carve(D_ * 4);
  float*  bc2  = (float*)carve(D_ * 4);
  float*  pmax = (float*)carve((long)B_ * 16 * D_ * 4);
  float*  psum = (float*)carve((long)B_ * 16 * D_ * 4);
  float*  cmax = (float*)carve((long)B_ * D_ * 4);
  float*  cinv = (float*)carve((long)B_ * D_ * 4);

  const dim3 blk(256, 1, 1);
  const int gCvtBig = (int)(NT / 4 / 256);
  const int gCvtW   = (int)(NW / 4 / 256);

  // ---- weight prep ----
  // w1 = [Wu_bf ; WV_bf] (one launch)
  cvt2_f32_bf16<<<dim3(gCvtW, 2), blk, 0, stream>>>(Wu, w1, WV, w1 + NW, NW / 4);
  // w2 = [Wl^T ; WA^T] (one launch)
  cvt_t2_f32_bf16<<<dim3(16, 16, 2), blk, 0, stream>>>(Wl, w2, WA, w2 + NW, D_, D_);
  // Wo -> wCat rows 1024..2047
  cvt_f32_bf16<<<dim3(gCvtW), blk, 0, stream>>>(Wo, wCat + NW, NW / 4);
  // batched weight compose: z=0: Wc = Wu·Wl -> wCat[0]; z=1: Wc2 = WV·WA -> wCat[2NW]
  gemm_nt<false, false><<<dim3(D_ / BN, D_ / BM, 2), blk, 0, stream>>>(
      w1, w2, nullptr, wCat, D_, D_, NW, NW, 2 * NW);
  // combined biases: bc = Wu·bl + bu ; bc2 = WV·bA + bV
  bias_comb2<<<dim3(D_ / 4, 2), blk, 0, stream>>>(Wu, bl, bu, bc, WV, bA, bV, bc2);
  // latent -> bf16
  cvt_f32_bf16<<<dim3(gCvtBig), blk, 0, stream>>>(lat, xBf, NT / 4);

  // ---- main pipeline ----
  // S1 (bufB) + ov (bufA) in one N=2048 GEMM over [Wc ; Wo]
  gemm_nt_dual<<<dim3(2 * D_ / BN, (B_ * T_) / BM, 1), blk, 0, stream>>>(
      xBf, wCat, bc, bo, bufB, bufA, D_);
  // l = row-softmax(S1) in place
  softmax_row<<<dim3(B_ * T_), blk, 0, stream>>>(bufB, bufB);
  // lT into xBf (latent dead)
  transpose_bf16<<<dim3(D_ / 64, T_ / 64, B_), blk, 0, stream>>>(bufB, xBf, T_, D_);
  // ovT into bufB (l dead)
  transpose_bf16<<<dim3(D_ / 64, T_ / 64, B_), blk, 0, stream>>>(bufA, bufB, T_, D_);
  // MT[d,e] = sum_q ovT[d,q]·lT[e,q], split-K=4 -> bf16 partials -> reduce
  gemm_nt_splitk<<<dim3(D_ / BN, D_ / BM, B_ * 4), blk, 0, stream>>>(bufB, xBf, part);
  reduce4_bf16<<<dim3((int)(B_ * NW / 8 / 256)), blk, 0, stream>>>(part, MT);
  // input -> bf16 (lT dead)
  cvt_f32_bf16<<<dim3(gCvtBig), blk, 0, stream>>>(inp, xBf, NT / 4);
  // S2 = inp @ Wc2^T + bc2 -> bufB (ovT dead)
  gemm_nt<false, true><<<dim3(D_ / BN, (B_ * T_) / BM, 1), blk, 0, stream>>>(
      xBf, wCat + 2 * NW, bc2, bufB, D_, D_, 0, 0, 0);
  // A = softmax over T_kv, in place
  colsoft_part<<<dim3(D_ / 256, 16, B_), blk, 0, stream>>>(bufB, pmax, psum);
  colsoft_comb<<<dim3(D_ / 256, B_, 1), blk, 0, stream>>>(pmax, psum, cmax, cinv);
  colsoft_norm<<<dim3((T_ * D_) / 2048, B_, 1), blk, 0, stream>>>(bufB, cmax, cinv);
  // o = A @ MT^T -> d_out (fp32)
  gemm_nt<true, false><<<dim3(D_ / BN, T_ / BM, B_), blk, 0, stream>>>(
      bufB, MT, nullptr, d_out, D_, D_,
      (long)T_ * D_, (long)D_ * D_, (long)T_ * D_);
}